// Round 2
// baseline (436.901 us; speedup 1.0000x reference)
//
#include <hip/hip_runtime.h>
#include <stdint.h>

// MultiHeadAttention  B=8, S=2048, D=768
// out = softmax((x Wq^T + bq)(x Wk^T + bk)^T / sqrt(D)) (x Wv^T + bv) Wp^T + bp
//
// Runtime dtype detection: inputs may be bf16 or fp32 (reference file says fp32,
// harness template says bf16). detect_dtype inspects x's low-16-bit halves of
// 32-bit words: for bf16 data they are genuine N(0,1) bf16 (~90% of |v| in
// [1/8,8]); for fp32 data they are mantissa noise (~2%). flag=1 -> bf16 native.
// If fp32: convert all 9 inputs to bf16 in ws, and write the final output fp32.
//
// Pipeline (all GEMMs NT, m97 structure: 128x128 tile, BK=32, global_load_lds
// width=16, 16x16x32 bf16 MFMA):
//   K1 x3 : Q,K,V projections (V stored transposed Vt[b][e][s])
//   K2    : E = exp(clamp(Q.K^T/sqrt(D), <=30))   (unnormalized softmax numerator)
//   K2b   : rl = 1/rowsum(E)
//   K3    : attn = (E @ V) * rl
//   K4    : out = attn@Wp^T + bp   (dtype per flag)

typedef __attribute__((ext_vector_type(8))) short short8;
typedef __attribute__((ext_vector_type(4))) float f32x4;

typedef const __attribute__((address_space(1))) void gvoid_t;
typedef __attribute__((address_space(3))) void lvoid_t;

__device__ __forceinline__ float b2f(unsigned short u) {
  union { unsigned int u; float f; } v;
  v.u = ((unsigned int)u) << 16;
  return v.f;
}
__device__ __forceinline__ unsigned short f2b(float f) {
  union { float f; unsigned int u; } v; v.f = f;
  unsigned int u = v.u;
  return (unsigned short)((u + 0x7fffu + ((u >> 16) & 1u)) >> 16);
}

// ---------------- dtype detection ----------------
__global__ void detect_dtype(const unsigned int* __restrict__ xu, int* __restrict__ flagp) {
  __shared__ int red[256];
  const int t = threadIdx.x;
  int cnt = 0;
  for (int i = t; i < 4096; i += 256) {
    unsigned int u = xu[i];
    float v = fabsf(b2f((unsigned short)(u & 0xffffu)));
    cnt += (v >= 0.125f && v <= 8.0f) ? 1 : 0;
  }
  red[t] = cnt;
  __syncthreads();
#pragma unroll
  for (int o = 128; o > 0; o >>= 1) {
    if (t < o) red[t] += red[t + o];
    __syncthreads();
  }
  if (t == 0) flagp[0] = (red[0] > 2048) ? 1 : 0;   // 1 = native bf16
}

// ---------------- fp32 -> bf16 conversion of all 9 inputs ----------------
struct Cvt9 {
  const void* s[9];
  unsigned short* d[9];
  long long n8[9];   // octet counts per segment
  long long total8;
};

__global__ __launch_bounds__(256) void convert_inputs(Cvt9 C, const int* __restrict__ flagp) {
  if (flagp[0] != 0) return;   // native bf16: GEMMs read original buffers
  long long g = (long long)blockIdx.x * 256 + threadIdx.x;
  if (g >= C.total8) return;
  int s = 0;
  long long off = g;
  while (off >= C.n8[s]) { off -= C.n8[s]; ++s; }
  const float* sf = (const float*)C.s[s] + off * 8;
  unsigned short* dp = C.d[s] + off * 8;
  float4 a = ((const float4*)sf)[0];
  float4 b = ((const float4*)sf)[1];
  uint4 o;
  o.x = (unsigned int)f2b(a.x) | ((unsigned int)f2b(a.y) << 16);
  o.y = (unsigned int)f2b(a.z) | ((unsigned int)f2b(a.w) << 16);
  o.z = (unsigned int)f2b(b.x) | ((unsigned int)f2b(b.y) << 16);
  o.w = (unsigned int)f2b(b.z) | ((unsigned int)f2b(b.w) << 16);
  *(uint4*)dp = o;
}

// ---------------- GEMM (NT): C[m][n] = sum_k A[m][k]*B[n][k] ----------------
// mode 0: C = acc + bias[col]                       (bf16 out)
// mode 1: Vt store: C[b][col][s] = acc + bias[col]  (bf16 out, transposed)
// mode 2: C = exp(min(acc*scale, 30))               (bf16 out)
// mode 3: C = acc * rl[b*2048+row]                  (bf16 out)
// mode 5: C = acc + bias[col], out dtype by flag    (final projection)
__global__ __launch_bounds__(256, 2) void gemm_nt(
    const unsigned short* __restrict__ A0, const unsigned short* __restrict__ A1,
    const unsigned short* __restrict__ B0, const unsigned short* __restrict__ B1,
    const unsigned short* __restrict__ bias0, const unsigned short* __restrict__ bias1,
    unsigned short* __restrict__ C, const float* __restrict__ rl,
    const int* __restrict__ flagp,
    int lda, int ldb, int ldc, int K,
    long long aBS, long long bBS, long long cBS,
    int mode, float scale)
{
  __shared__ unsigned short smem[17408];  // staging A[4096]+B[4096]; mode1 transpose [128][136]
  unsigned short* As = smem;
  unsigned short* Bs = smem + 4096;

  const int flg = flagp[0];
  const unsigned short* A    = flg ? A0 : A1;
  const unsigned short* B    = flg ? B0 : B1;
  const unsigned short* bias = flg ? bias0 : bias1;

  const int t    = threadIdx.x;
  const int w    = t >> 6;
  const int lane = t & 63;
  const int lo   = lane & 15;
  const int quad = lane >> 4;
  const int wr   = w >> 1;
  const int wc   = w & 1;
  const int m0   = blockIdx.x * 128;
  const int n0   = blockIdx.y * 128;
  const int bz   = blockIdx.z;

  const unsigned short* Ab = A + (size_t)bz * aBS;
  const unsigned short* Bb = B + (size_t)bz * bBS;

  f32x4 acc[4][4] = {};

  const int srow  = t >> 2;        // 0..63 staging row within 64-row round
  const int skoff = (t & 3) * 8;   // k-offset in elements

  for (int k0 = 0; k0 < K; k0 += 32) {
#pragma unroll
    for (int r = 0; r < 2; ++r) {
      const unsigned short* ga = Ab + (size_t)(m0 + r * 64 + srow) * lda + (k0 + skoff);
      __builtin_amdgcn_global_load_lds((gvoid_t*)ga, (lvoid_t*)(As + r * 2048 + w * 512), 16, 0, 0);
      const unsigned short* gb = Bb + (size_t)(n0 + r * 64 + srow) * ldb + (k0 + skoff);
      __builtin_amdgcn_global_load_lds((gvoid_t*)gb, (lvoid_t*)(Bs + r * 2048 + w * 512), 16, 0, 0);
    }
    __syncthreads();

    short8 af[4], bf[4];
#pragma unroll
    for (int i = 0; i < 4; ++i)
      af[i] = *(const short8*)(As + (wr * 64 + i * 16 + lo) * 32 + quad * 8);
#pragma unroll
    for (int j = 0; j < 4; ++j)
      bf[j] = *(const short8*)(Bs + (wc * 64 + j * 16 + lo) * 32 + quad * 8);

#pragma unroll
    for (int i = 0; i < 4; ++i)
#pragma unroll
      for (int j = 0; j < 4; ++j)
        acc[i][j] = __builtin_amdgcn_mfma_f32_16x16x32_bf16(af[i], bf[j], acc[i][j], 0, 0, 0);
    __syncthreads();
  }

  if (mode == 1) {
    // LDS transpose [col][row] (pad 136), then coalesced store along s into Vt[b][e][s]
    unsigned short* Ls = smem;
#pragma unroll
    for (int i = 0; i < 4; ++i) {
      const int rt = wr * 64 + i * 16 + quad * 4;
#pragma unroll
      for (int j = 0; j < 4; ++j) {
        const int ct = wc * 64 + j * 16 + lo;
        const float bv = b2f(bias[n0 + ct]);
        ushort4 pk;
        pk.x = f2b(acc[i][j][0] + bv);
        pk.y = f2b(acc[i][j][1] + bv);
        pk.z = f2b(acc[i][j][2] + bv);
        pk.w = f2b(acc[i][j][3] + bv);
        *(ushort4*)(Ls + ct * 136 + rt) = pk;
      }
    }
    __syncthreads();
    const int bb  = m0 >> 11;
    const int sin = m0 & 2047;
    unsigned short* Cb = C + (size_t)bb * cBS;
#pragma unroll
    for (int e0 = 0; e0 < 128; e0 += 16) {
      const int et = e0 + (t >> 4);
      const int st = (t & 15) * 8;
      uint4 val = *(const uint4*)(Ls + et * 136 + st);
      *(uint4*)(Cb + (size_t)(n0 + et) * ldc + (sin + st)) = val;
    }
    return;
  }

  unsigned short* Cb = C + (size_t)bz * cBS;
  float* Cf = (float*)C + (size_t)bz * cBS;
  const bool f32out = (mode == 5) && (flg == 0);
#pragma unroll
  for (int j = 0; j < 4; ++j) {
    const int col = n0 + wc * 64 + j * 16 + lo;
    const float bv = (mode == 0 || mode == 5) ? b2f(bias[col]) : 0.0f;
#pragma unroll
    for (int i = 0; i < 4; ++i) {
      const int rowb = m0 + wr * 64 + i * 16 + quad * 4;
#pragma unroll
      for (int r = 0; r < 4; ++r) {
        const int row = rowb + r;
        float v = acc[i][j][r];
        if (mode == 0 || mode == 5) v = v + bv;
        else if (mode == 2)         v = __expf(fminf(v * scale, 30.0f));
        else                        v = v * rl[(size_t)bz * 2048 + row];
        if (f32out) Cf[(size_t)row * ldc + col] = v;
        else        Cb[(size_t)row * ldc + col] = f2b(v);
      }
    }
  }
}

// rl[row] = 1 / sum_k E[row][k]
__global__ __launch_bounds__(256) void rowsum_inv(const unsigned short* __restrict__ E,
                                                  float* __restrict__ rl)
{
  __shared__ float red[256];
  const int row = blockIdx.x;
  const int t = threadIdx.x;
  const unsigned short* er = E + (size_t)row * 2048;
  uint4 v = *(const uint4*)(er + t * 8);
  unsigned int u[4] = {v.x, v.y, v.z, v.w};
  float s = 0.f;
#pragma unroll
  for (int q = 0; q < 4; ++q)
    s += b2f((unsigned short)(u[q] & 0xffffu)) + b2f((unsigned short)(u[q] >> 16));
  red[t] = s;
  __syncthreads();
#pragma unroll
  for (int off = 128; off > 0; off >>= 1) {
    if (t < off) red[t] += red[t + off];
    __syncthreads();
  }
  if (t == 0) rl[row] = 1.0f / fmaxf(red[0], 1e-30f);
}

extern "C" void kernel_launch(void* const* d_in, const int* in_sizes, int n_in,
                              void* d_out, int out_size, void* d_ws, size_t ws_size,
                              hipStream_t stream) {
  (void)in_sizes; (void)n_in; (void)out_size; (void)ws_size;
  const unsigned short* x  = (const unsigned short*)d_in[0];
  const unsigned short* Wq = (const unsigned short*)d_in[1];
  const unsigned short* bq = (const unsigned short*)d_in[2];
  const unsigned short* Wk = (const unsigned short*)d_in[3];
  const unsigned short* bk = (const unsigned short*)d_in[4];
  const unsigned short* Wv = (const unsigned short*)d_in[5];
  const unsigned short* bv = (const unsigned short*)d_in[6];
  const unsigned short* Wp = (const unsigned short*)d_in[7];
  const unsigned short* bp = (const unsigned short*)d_in[8];

  char* ws = (char*)d_ws;
  int*   flagp = (int*)ws;
  float* rl    = (float*)(ws + 4096);                         // 64 KiB
  unsigned short* wcv = (unsigned short*)(ws + ((size_t)1 << 20));   // 4.51 MiB conv weights
  unsigned short* qb  = (unsigned short*)(ws + ((size_t)8  << 20));  // 24 MiB
  unsigned short* kb  = (unsigned short*)(ws + ((size_t)32 << 20));  // 24 MiB
  unsigned short* vt  = (unsigned short*)(ws + ((size_t)56 << 20));  // 24 MiB  Vt[b][e][s]
  unsigned short* eb  = (unsigned short*)(ws + ((size_t)80 << 20));  // 64 MiB  E[b][q][k]
  unsigned short* xb  = eb;   // converted x aliases E: x dead before K2 writes E
  unsigned short* attn = qb;  // Q dead after K2

  // converted weight/bias sub-buffers
  unsigned short* wqb = wcv;
  unsigned short* bqb = wcv + 589824;
  unsigned short* wkb = wcv + 590592;
  unsigned short* bkb = wcv + 1180416;
  unsigned short* wvb = wcv + 1181184;
  unsigned short* bvb = wcv + 1771008;
  unsigned short* wpb = wcv + 1771776;
  unsigned short* bpb = wcv + 2361600;

  const float inv_scale = 0.036084391824351615f;  // 1/sqrt(768)
  dim3 blk(256);

  // D0: dtype flag
  detect_dtype<<<1, 256, 0, stream>>>((const unsigned int*)d_in[0], flagp);

  // D1: convert (no-op when native bf16)
  Cvt9 cv;
  cv.s[0] = d_in[0]; cv.d[0] = xb;  cv.n8[0] = 12582912 / 8;
  cv.s[1] = d_in[1]; cv.d[1] = wqb; cv.n8[1] = 589824 / 8;
  cv.s[2] = d_in[2]; cv.d[2] = bqb; cv.n8[2] = 768 / 8;
  cv.s[3] = d_in[3]; cv.d[3] = wkb; cv.n8[3] = 589824 / 8;
  cv.s[4] = d_in[4]; cv.d[4] = bkb; cv.n8[4] = 768 / 8;
  cv.s[5] = d_in[5]; cv.d[5] = wvb; cv.n8[5] = 589824 / 8;
  cv.s[6] = d_in[6]; cv.d[6] = bvb; cv.n8[6] = 768 / 8;
  cv.s[7] = d_in[7]; cv.d[7] = wpb; cv.n8[7] = 589824 / 8;
  cv.s[8] = d_in[8]; cv.d[8] = bpb; cv.n8[8] = 768 / 8;
  cv.total8 = (12582912 + 4 * (589824 + 768)) / 8;  // 1868160
  convert_inputs<<<(unsigned)((cv.total8 + 255) / 256), blk, 0, stream>>>(cv, flagp);

  // K1: projections (NT, M=16384, N=768, K=768)
  gemm_nt<<<dim3(128, 6, 1), blk, 0, stream>>>(x, xb, Wq, wqb, bq, bqb, qb, nullptr, flagp,
      768, 768, 768, 768, 0, 0, 0, 0, 1.f);
  gemm_nt<<<dim3(128, 6, 1), blk, 0, stream>>>(x, xb, Wk, wkb, bk, bkb, kb, nullptr, flagp,
      768, 768, 768, 768, 0, 0, 0, 0, 1.f);
  gemm_nt<<<dim3(128, 6, 1), blk, 0, stream>>>(x, xb, Wv, wvb, bv, bvb, vt, nullptr, flagp,
      768, 768, 2048, 768, 0, 0, (long long)768 * 2048, 1, 1.f);

  // K2: E = exp(Q.K^T/sqrt(D))  (per batch, M=N=2048, K=768)
  gemm_nt<<<dim3(16, 16, 8), blk, 0, stream>>>(qb, qb, kb, kb, nullptr, nullptr, eb, nullptr, flagp,
      768, 768, 2048, 768,
      (long long)2048 * 768, (long long)2048 * 768, (long long)2048 * 2048, 2, inv_scale);

  // K2b: row-sum reciprocals
  rowsum_inv<<<16384, 256, 0, stream>>>(eb, rl);

  // K3: attn = (E @ V) * rl  (per batch, M=2048, N=768, K=2048, B = Vt)
  gemm_nt<<<dim3(16, 6, 8), blk, 0, stream>>>(eb, eb, vt, vt, nullptr, nullptr, attn, rl, flagp,
      2048, 2048, 768, 2048,
      (long long)2048 * 2048, (long long)768 * 2048, (long long)2048 * 768, 3, 1.f);

  // K4: out = attn@Wp^T + bp  (M=16384, N=768, K=768; out dtype per flag)
  gemm_nt<<<dim3(128, 6, 1), blk, 0, stream>>>(attn, attn, Wp, wpb, bp, bpb,
      (unsigned short*)d_out, nullptr, flagp,
      768, 768, 768, 768, 0, 0, 0, 5, 1.f);
}

// Round 3
// 372.961 us; speedup vs baseline: 1.1714x; 1.1714x over previous
//
#include <hip/hip_runtime.h>
#include <stdint.h>

// MultiHeadAttention  B=8, S=2048, D=768  (fp32 in/out detected at runtime; bf16 MFMA compute)
//
// Pipeline:
//   detect  : dtype flag (1 = native bf16, 0 = fp32 -> convert)
//   convert : all 9 inputs fp32->bf16 into ws (no-op if native bf16)
//   qkv_k   : fused Q/K/V projections, one dispatch (grid 128x18); V stored transposed Vt[b][e][s]
//   score_k : E = exp(min(Q.K^T/sqrt(D),30)) bf16 + fused rowsum atomicAdd -> rl
//   inv_k   : rl = 1/rl
//   pv_k    : attn = (E @ V) * rl
//   out_k   : out = attn@Wp^T + bp  (fp32 or bf16 per flag)
//
// GEMM core: m97 structure (128x128 tile, BK=32, global_load_lds width=16,
// 16x16x32 bf16 MFMA). All epilogues stage the C-tile through LDS and store
// 16B-vectorized (fixes the 2x HBM write amplification measured in R2).

typedef __attribute__((ext_vector_type(8))) short short8;
typedef __attribute__((ext_vector_type(4))) float f32x4;

typedef const __attribute__((address_space(1))) void gvoid_t;
typedef __attribute__((address_space(3))) void lvoid_t;

__device__ __forceinline__ float b2f(unsigned short u) {
  union { unsigned int u; float f; } v;
  v.u = ((unsigned int)u) << 16;
  return v.f;
}
__device__ __forceinline__ unsigned short f2b(float f) {
  union { float f; unsigned int u; } v; v.f = f;
  unsigned int u = v.u;
  return (unsigned short)((u + 0x7fffu + ((u >> 16) & 1u)) >> 16);
}

// ---------------- dtype detection ----------------
__global__ void detect_dtype(const unsigned int* __restrict__ xu, int* __restrict__ flagp) {
  __shared__ int red[256];
  const int t = threadIdx.x;
  int cnt = 0;
  for (int i = t; i < 4096; i += 256) {
    unsigned int u = xu[i];
    float v = fabsf(b2f((unsigned short)(u & 0xffffu)));
    cnt += (v >= 0.125f && v <= 8.0f) ? 1 : 0;
  }
  red[t] = cnt;
  __syncthreads();
#pragma unroll
  for (int o = 128; o > 0; o >>= 1) {
    if (t < o) red[t] += red[t + o];
    __syncthreads();
  }
  if (t == 0) flagp[0] = (red[0] > 2048) ? 1 : 0;
}

// ---------------- fp32 -> bf16 conversion ----------------
struct Cvt9 {
  const void* s[9];
  unsigned short* d[9];
  long long n8[9];
  long long total8;
};

__global__ __launch_bounds__(256) void convert_inputs(Cvt9 C, const int* __restrict__ flagp) {
  if (flagp[0] != 0) return;
  long long g = (long long)blockIdx.x * 256 + threadIdx.x;
  if (g >= C.total8) return;
  int s = 0;
  long long off = g;
  while (off >= C.n8[s]) { off -= C.n8[s]; ++s; }
  const float* sf = (const float*)C.s[s] + off * 8;
  unsigned short* dp = C.d[s] + off * 8;
  float4 a = ((const float4*)sf)[0];
  float4 b = ((const float4*)sf)[1];
  uint4 o;
  o.x = (unsigned int)f2b(a.x) | ((unsigned int)f2b(a.y) << 16);
  o.y = (unsigned int)f2b(a.z) | ((unsigned int)f2b(a.w) << 16);
  o.z = (unsigned int)f2b(b.x) | ((unsigned int)f2b(b.y) << 16);
  o.w = (unsigned int)f2b(b.z) | ((unsigned int)f2b(b.w) << 16);
  *(uint4*)dp = o;
}

// ---------------- GEMM core (NT): acc += A[m0+128][k] * B[n0+128][k]^T ----------------
__device__ __forceinline__ void gemm_core(
    const unsigned short* __restrict__ Ab, const unsigned short* __restrict__ Bb,
    int lda, int ldb, int K, int m0, int n0,
    unsigned short* As, unsigned short* Bs, f32x4 (&acc)[4][4])
{
  const int t    = threadIdx.x;
  const int w    = t >> 6;
  const int lane = t & 63;
  const int lo   = lane & 15;
  const int quad = lane >> 4;
  const int wr   = w >> 1;
  const int wc   = w & 1;
  const int srow  = t >> 2;
  const int skoff = (t & 3) * 8;

  for (int k0 = 0; k0 < K; k0 += 32) {
#pragma unroll
    for (int r = 0; r < 2; ++r) {
      const unsigned short* ga = Ab + (size_t)(m0 + r * 64 + srow) * lda + (k0 + skoff);
      __builtin_amdgcn_global_load_lds((gvoid_t*)ga, (lvoid_t*)(As + r * 2048 + w * 512), 16, 0, 0);
      const unsigned short* gb = Bb + (size_t)(n0 + r * 64 + srow) * ldb + (k0 + skoff);
      __builtin_amdgcn_global_load_lds((gvoid_t*)gb, (lvoid_t*)(Bs + r * 2048 + w * 512), 16, 0, 0);
    }
    __syncthreads();

    short8 af[4], bf[4];
#pragma unroll
    for (int i = 0; i < 4; ++i)
      af[i] = *(const short8*)(As + (wr * 64 + i * 16 + lo) * 32 + quad * 8);
#pragma unroll
    for (int j = 0; j < 4; ++j)
      bf[j] = *(const short8*)(Bs + (wc * 64 + j * 16 + lo) * 32 + quad * 8);

#pragma unroll
    for (int i = 0; i < 4; ++i)
#pragma unroll
      for (int j = 0; j < 4; ++j)
        acc[i][j] = __builtin_amdgcn_mfma_f32_16x16x32_bf16(af[i], bf[j], acc[i][j], 0, 0, 0);
    __syncthreads();
  }
}

// ---------------- epilogue helpers ----------------
// mode 0: v += bias[ct] ; mode 2: v = exp(min(v*scale,30)) ; mode 3: v *= rlrow[rt+r]
__device__ __forceinline__ void tile_to_lds(
    unsigned short* Ls, f32x4 (&acc)[4][4], int mode,
    const unsigned short* bias_n0, const float* rlrow, float scale)
{
  const int t = threadIdx.x;
  const int w = t >> 6, lane = t & 63;
  const int lo = lane & 15, quad = lane >> 4, wr = w >> 1, wc = w & 1;
#pragma unroll
  for (int j = 0; j < 4; ++j) {
    const int ct = wc * 64 + j * 16 + lo;
    const float bv = (mode == 0) ? b2f(bias_n0[ct]) : 0.f;
#pragma unroll
    for (int i = 0; i < 4; ++i) {
      const int rt = wr * 64 + i * 16 + quad * 4;
#pragma unroll
      for (int r = 0; r < 4; ++r) {
        float v = acc[i][j][r];
        if (mode == 0)      v += bv;
        else if (mode == 2) v = __expf(fminf(v * scale, 30.f));
        else                v *= rlrow[rt + r];
        Ls[(rt + r) * 136 + ct] = f2b(v);
      }
    }
  }
  __syncthreads();
}

__device__ __forceinline__ void lds_to_global_bf16(
    const unsigned short* Ls, unsigned short* Cg, int ldc)
{
  const int t = threadIdx.x;
  const int cr = t >> 4, cc = (t & 15) * 8;
#pragma unroll
  for (int r0 = 0; r0 < 128; r0 += 16) {
    uint4 v = *(const uint4*)(Ls + (r0 + cr) * 136 + cc);
    *(uint4*)(Cg + (size_t)(r0 + cr) * ldc + cc) = v;
  }
}

// ---------------- qkv: fused projections ----------------
__global__ __launch_bounds__(256, 2) void qkv_k(
    const unsigned short* __restrict__ x0, const unsigned short* __restrict__ x1,
    const unsigned short* __restrict__ Wq0, const unsigned short* __restrict__ Wq1,
    const unsigned short* __restrict__ bq0, const unsigned short* __restrict__ bq1,
    const unsigned short* __restrict__ Wk0, const unsigned short* __restrict__ Wk1,
    const unsigned short* __restrict__ bk0, const unsigned short* __restrict__ bk1,
    const unsigned short* __restrict__ Wv0, const unsigned short* __restrict__ Wv1,
    const unsigned short* __restrict__ bv0, const unsigned short* __restrict__ bv1,
    unsigned short* __restrict__ qb, unsigned short* __restrict__ kb,
    unsigned short* __restrict__ vt, const int* __restrict__ flagp)
{
  __shared__ unsigned short smem[17408];
  const int flg = flagp[0];
  const int sel = blockIdx.y / 6;
  const int n0  = (blockIdx.y % 6) * 128;
  const int m0  = blockIdx.x * 128;

  const unsigned short* A = flg ? x0 : x1;
  const unsigned short* W;
  const unsigned short* bi;
  if (sel == 0)      { W = flg ? Wq0 : Wq1; bi = flg ? bq0 : bq1; }
  else if (sel == 1) { W = flg ? Wk0 : Wk1; bi = flg ? bk0 : bk1; }
  else               { W = flg ? Wv0 : Wv1; bi = flg ? bv0 : bv1; }

  f32x4 acc[4][4] = {};
  gemm_core(A, W, 768, 768, 768, m0, n0, smem, smem + 4096, acc);

  const int t = threadIdx.x;
  const int w = t >> 6, lane = t & 63;
  const int lo = lane & 15, quad = lane >> 4, wr = w >> 1, wc = w & 1;

  if (sel < 2) {
    tile_to_lds(smem, acc, 0, bi + n0, nullptr, 0.f);
    unsigned short* dst = (sel == 0) ? qb : kb;
    lds_to_global_bf16(smem, dst + (size_t)m0 * 768 + n0, 768);
    return;
  }

  // V: transpose epilogue into Vt[b][e][s]  (Ls as [col][row], stride 136)
  unsigned short* Ls = smem;
#pragma unroll
  for (int i = 0; i < 4; ++i) {
    const int rt = wr * 64 + i * 16 + quad * 4;
#pragma unroll
    for (int j = 0; j < 4; ++j) {
      const int ct = wc * 64 + j * 16 + lo;
      const float bvv = b2f(bi[n0 + ct]);
      ushort4 pk;
      pk.x = f2b(acc[i][j][0] + bvv);
      pk.y = f2b(acc[i][j][1] + bvv);
      pk.z = f2b(acc[i][j][2] + bvv);
      pk.w = f2b(acc[i][j][3] + bvv);
      *(ushort4*)(Ls + ct * 136 + rt) = pk;
    }
  }
  __syncthreads();
  const int bb  = m0 >> 11;
  const int sin = m0 & 2047;
  unsigned short* Cb = vt + (size_t)bb * (768 * 2048);
#pragma unroll
  for (int e0 = 0; e0 < 128; e0 += 16) {
    const int et = e0 + (t >> 4);
    const int st = (t & 15) * 8;
    uint4 val = *(const uint4*)(Ls + et * 136 + st);
    *(uint4*)(Cb + (size_t)(n0 + et) * 2048 + (sin + st)) = val;
  }
}

// ---------------- score: E = exp(QK^T/sqrt(D)) + fused rowsum ----------------
__global__ __launch_bounds__(256, 2) void score_k(
    const unsigned short* __restrict__ Q, const unsigned short* __restrict__ Kb,
    unsigned short* __restrict__ E, float* __restrict__ rl, float scale)
{
  __shared__ unsigned short smem[17408];
  const int m0 = blockIdx.x * 128, n0 = blockIdx.y * 128, bz = blockIdx.z;

  f32x4 acc[4][4] = {};
  gemm_core(Q + (size_t)bz * 1572864, Kb + (size_t)bz * 1572864,
            768, 768, 768, m0, n0, smem, smem + 4096, acc);

  tile_to_lds(smem, acc, 2, nullptr, nullptr, scale);
  lds_to_global_bf16(smem, E + (size_t)bz * 4194304 + (size_t)m0 * 2048 + n0, 2048);

  // fused partial rowsum from the staged LDS tile
  const int t = threadIdx.x;
  const int row = t >> 1, half = t & 1;
  const unsigned short* lr = smem + row * 136 + half * 64;
  float s = 0.f;
#pragma unroll
  for (int q8 = 0; q8 < 8; ++q8) {
    uint4 v = *(const uint4*)(lr + q8 * 8);
    unsigned int uu[4] = {v.x, v.y, v.z, v.w};
#pragma unroll
    for (int c = 0; c < 4; ++c)
      s += b2f((unsigned short)(uu[c] & 0xffffu)) + b2f((unsigned short)(uu[c] >> 16));
  }
  s += __shfl_xor(s, 1);
  if (half == 0) atomicAdd(rl + bz * 2048 + m0 + row, s);
}

__global__ __launch_bounds__(256) void inv_k(float* __restrict__ rl) {
  const int i = blockIdx.x * 256 + threadIdx.x;
  if (i < 16384) rl[i] = 1.0f / fmaxf(rl[i], 1e-30f);
}

// ---------------- pv: attn = (E @ V) * rl ----------------
__global__ __launch_bounds__(256, 2) void pv_k(
    const unsigned short* __restrict__ E, const unsigned short* __restrict__ Vt,
    const float* __restrict__ rl, unsigned short* __restrict__ attn)
{
  __shared__ unsigned short smem[17408];
  const int m0 = blockIdx.x * 128, n0 = blockIdx.y * 128, bz = blockIdx.z;

  f32x4 acc[4][4] = {};
  gemm_core(E + (size_t)bz * 4194304, Vt + (size_t)bz * 1572864,
            2048, 2048, 2048, m0, n0, smem, smem + 4096, acc);

  tile_to_lds(smem, acc, 3, nullptr, rl + bz * 2048 + m0, 0.f);
  lds_to_global_bf16(smem, attn + (size_t)bz * 1572864 + (size_t)m0 * 768 + n0, 768);
}

// ---------------- out: final projection ----------------
__global__ __launch_bounds__(256, 2) void out_k(
    const unsigned short* __restrict__ attn,
    const unsigned short* __restrict__ Wp0, const unsigned short* __restrict__ Wp1,
    const unsigned short* __restrict__ bp0, const unsigned short* __restrict__ bp1,
    void* __restrict__ outp, const int* __restrict__ flagp)
{
  __shared__ unsigned short smem[17408];
  const int flg = flagp[0];
  const int m0 = blockIdx.x * 128, n0 = blockIdx.y * 128;
  const unsigned short* W  = flg ? Wp0 : Wp1;
  const unsigned short* bi = flg ? bp0 : bp1;

  f32x4 acc[4][4] = {};
  gemm_core(attn, W, 768, 768, 768, m0, n0, smem, smem + 4096, acc);

  if (flg) {
    tile_to_lds(smem, acc, 0, bi + n0, nullptr, 0.f);
    lds_to_global_bf16(smem, (unsigned short*)outp + (size_t)m0 * 768 + n0, 768);
    return;
  }

  // fp32 output: two half-tiles (cols 0-63 then 64-127) staged as float through LDS
  const int t = threadIdx.x;
  const int w = t >> 6, lane = t & 63;
  const int lo = lane & 15, quad = lane >> 4, wr = w >> 1, wc = w & 1;
  float* Lf = (float*)smem;     // 128 x 68 floats = 34816 B
  float* Of = (float*)outp;
#pragma unroll
  for (int h = 0; h < 2; ++h) {
    __syncthreads();
    if (wc == h) {
#pragma unroll
      for (int j = 0; j < 4; ++j) {
        const int cl = j * 16 + lo;                 // 0..63 within half
        const float bvv = b2f(bi[n0 + h * 64 + cl]);
#pragma unroll
        for (int i = 0; i < 4; ++i) {
          const int rt = wr * 64 + i * 16 + quad * 4;
#pragma unroll
          for (int r = 0; r < 4; ++r)
            Lf[(rt + r) * 68 + cl] = acc[i][j][r] + bvv;
        }
      }
    }
    __syncthreads();
    const int cr = t >> 4, cc = (t & 15) * 4;
#pragma unroll
    for (int r0 = 0; r0 < 128; r0 += 16) {
      float4 v = *(const float4*)(Lf + (r0 + cr) * 68 + cc);
      *(float4*)(Of + (size_t)(m0 + r0 + cr) * 768 + n0 + h * 64 + cc) = v;
    }
  }
}

extern "C" void kernel_launch(void* const* d_in, const int* in_sizes, int n_in,
                              void* d_out, int out_size, void* d_ws, size_t ws_size,
                              hipStream_t stream) {
  (void)in_sizes; (void)n_in; (void)out_size; (void)ws_size;
  const unsigned short* x  = (const unsigned short*)d_in[0];
  const unsigned short* Wq = (const unsigned short*)d_in[1];
  const unsigned short* bq = (const unsigned short*)d_in[2];
  const unsigned short* Wk = (const unsigned short*)d_in[3];
  const unsigned short* bk = (const unsigned short*)d_in[4];
  const unsigned short* Wv = (const unsigned short*)d_in[5];
  const unsigned short* bv = (const unsigned short*)d_in[6];
  const unsigned short* Wp = (const unsigned short*)d_in[7];
  const unsigned short* bp = (const unsigned short*)d_in[8];

  char* ws = (char*)d_ws;
  int*   flagp = (int*)ws;
  float* rl    = (float*)(ws + 4096);
  unsigned short* wcv = (unsigned short*)(ws + ((size_t)1 << 20));
  unsigned short* qb  = (unsigned short*)(ws + ((size_t)8  << 20));
  unsigned short* kb  = (unsigned short*)(ws + ((size_t)32 << 20));
  unsigned short* vt  = (unsigned short*)(ws + ((size_t)56 << 20));
  unsigned short* eb  = (unsigned short*)(ws + ((size_t)80 << 20));
  unsigned short* xb  = eb;     // converted x aliases E (x dead before score_k writes E)
  unsigned short* attn = qb;    // Q dead after score_k

  unsigned short* wqb = wcv;
  unsigned short* bqb = wcv + 589824;
  unsigned short* wkb = wcv + 590592;
  unsigned short* bkb = wcv + 1180416;
  unsigned short* wvb = wcv + 1181184;
  unsigned short* bvb = wcv + 1771008;
  unsigned short* wpb = wcv + 1771776;
  unsigned short* bpb = wcv + 2361600;

  const float inv_scale = 0.036084391824351615f;  // 1/sqrt(768)
  dim3 blk(256);

  detect_dtype<<<1, 256, 0, stream>>>((const unsigned int*)d_in[0], flagp);

  Cvt9 cv;
  cv.s[0] = d_in[0]; cv.d[0] = xb;  cv.n8[0] = 12582912 / 8;
  cv.s[1] = d_in[1]; cv.d[1] = wqb; cv.n8[1] = 589824 / 8;
  cv.s[2] = d_in[2]; cv.d[2] = bqb; cv.n8[2] = 768 / 8;
  cv.s[3] = d_in[3]; cv.d[3] = wkb; cv.n8[3] = 589824 / 8;
  cv.s[4] = d_in[4]; cv.d[4] = bkb; cv.n8[4] = 768 / 8;
  cv.s[5] = d_in[5]; cv.d[5] = wvb; cv.n8[5] = 589824 / 8;
  cv.s[6] = d_in[6]; cv.d[6] = bvb; cv.n8[6] = 768 / 8;
  cv.s[7] = d_in[7]; cv.d[7] = wpb; cv.n8[7] = 589824 / 8;
  cv.s[8] = d_in[8]; cv.d[8] = bpb; cv.n8[8] = 768 / 8;
  cv.total8 = (12582912 + 4 * (589824 + 768)) / 8;
  convert_inputs<<<(unsigned)((cv.total8 + 255) / 256), blk, 0, stream>>>(cv, flagp);

  hipMemsetAsync(rl, 0, 16384 * sizeof(float), stream);

  qkv_k<<<dim3(128, 18, 1), blk, 0, stream>>>(
      x, xb, Wq, wqb, bq, bqb, Wk, wkb, bk, bkb, Wv, wvb, bv, bvb,
      qb, kb, vt, flagp);

  score_k<<<dim3(16, 16, 8), blk, 0, stream>>>(qb, kb, eb, rl, inv_scale);

  inv_k<<<64, blk, 0, stream>>>(rl);

  pv_k<<<dim3(16, 6, 8), blk, 0, stream>>>(eb, vt, rl, attn);

  out_k<<<dim3(128, 6, 1), blk, 0, stream>>>(attn, Wp, wpb, bp, bpb, d_out, flagp);
}

// Round 4
// 371.687 us; speedup vs baseline: 1.1755x; 1.0034x over previous
//
#include <hip/hip_runtime.h>
#include <stdint.h>

// MultiHeadAttention  B=8, S=2048, D=768  (fp32 in/out detected at runtime; bf16 MFMA compute)
//
// Pipeline:
//   detect  : dtype flag (1 = native bf16, 0 = fp32 -> convert)
//   convert : all 9 inputs fp32->bf16 into ws (no-op if native bf16)
//   qkv_k   : fused Q/K/V projections, one dispatch (grid 128x18); V stored transposed Vt[b][e][s]
//   score_k : E = exp(min(Q.K^T/sqrt(D),30)) bf16 + fused rowsum atomicAdd -> rl
//   inv_k   : rl = 1/rl
//   pv_k    : attn = (E @ V) * rl
//   out_k   : out = attn@Wp^T + bp  (fp32 or bf16 per flag)
//
// GEMM core: m97 structure upgraded to BK=64 (two 32-wide LDS sub-buffers, one
// barrier pair per 64-k chunk -> 32 MFMA/wave between barriers, halving the
// vmcnt(0) barrier-drain count that limits the BK=32 structure to ~670 TF here).
// All epilogues stage C through LDS and store 16B-vectorized.

typedef __attribute__((ext_vector_type(8))) short short8;
typedef __attribute__((ext_vector_type(4))) float f32x4;

typedef const __attribute__((address_space(1))) void gvoid_t;
typedef __attribute__((address_space(3))) void lvoid_t;

__device__ __forceinline__ float b2f(unsigned short u) {
  union { unsigned int u; float f; } v;
  v.u = ((unsigned int)u) << 16;
  return v.f;
}
__device__ __forceinline__ unsigned short f2b(float f) {
  union { float f; unsigned int u; } v; v.f = f;
  unsigned int u = v.u;
  return (unsigned short)((u + 0x7fffu + ((u >> 16) & 1u)) >> 16);
}

// ---------------- dtype detection ----------------
__global__ void detect_dtype(const unsigned int* __restrict__ xu, int* __restrict__ flagp) {
  __shared__ int red[256];
  const int t = threadIdx.x;
  int cnt = 0;
  for (int i = t; i < 4096; i += 256) {
    unsigned int u = xu[i];
    float v = fabsf(b2f((unsigned short)(u & 0xffffu)));
    cnt += (v >= 0.125f && v <= 8.0f) ? 1 : 0;
  }
  red[t] = cnt;
  __syncthreads();
#pragma unroll
  for (int o = 128; o > 0; o >>= 1) {
    if (t < o) red[t] += red[t + o];
    __syncthreads();
  }
  if (t == 0) flagp[0] = (red[0] > 2048) ? 1 : 0;
}

// ---------------- fp32 -> bf16 conversion ----------------
struct Cvt9 {
  const void* s[9];
  unsigned short* d[9];
  long long n8[9];
  long long total8;
};

__global__ __launch_bounds__(256) void convert_inputs(Cvt9 C, const int* __restrict__ flagp) {
  if (flagp[0] != 0) return;
  long long g = (long long)blockIdx.x * 256 + threadIdx.x;
  if (g >= C.total8) return;
  int s = 0;
  long long off = g;
  while (off >= C.n8[s]) { off -= C.n8[s]; ++s; }
  const float* sf = (const float*)C.s[s] + off * 8;
  unsigned short* dp = C.d[s] + off * 8;
  float4 a = ((const float4*)sf)[0];
  float4 b = ((const float4*)sf)[1];
  uint4 o;
  o.x = (unsigned int)f2b(a.x) | ((unsigned int)f2b(a.y) << 16);
  o.y = (unsigned int)f2b(a.z) | ((unsigned int)f2b(a.w) << 16);
  o.z = (unsigned int)f2b(b.x) | ((unsigned int)f2b(b.y) << 16);
  o.w = (unsigned int)f2b(b.z) | ((unsigned int)f2b(b.w) << 16);
  *(uint4*)dp = o;
}

// ---------------- GEMM core (NT, BK=64): acc += A[m0+128][k] * B[n0+128][k]^T ----
// LDS layout per matrix: [2 chunks][128 rows][32 k]  (chunk c at +c*4096 elems)
__device__ __forceinline__ void gemm_core(
    const unsigned short* __restrict__ Ab, const unsigned short* __restrict__ Bb,
    int lda, int ldb, int K, int m0, int n0,
    unsigned short* As, unsigned short* Bs, f32x4 (&acc)[4][4])
{
  const int t    = threadIdx.x;
  const int w    = t >> 6;
  const int lane = t & 63;
  const int lo   = lane & 15;
  const int quad = lane >> 4;
  const int wr   = w >> 1;
  const int wc   = w & 1;
  const int srow  = t >> 2;
  const int skoff = (t & 3) * 8;

  for (int k0 = 0; k0 < K; k0 += 64) {
#pragma unroll
    for (int c = 0; c < 2; ++c) {
#pragma unroll
      for (int r = 0; r < 2; ++r) {
        const unsigned short* ga = Ab + (size_t)(m0 + r * 64 + srow) * lda + (k0 + c * 32 + skoff);
        __builtin_amdgcn_global_load_lds((gvoid_t*)ga, (lvoid_t*)(As + c * 4096 + r * 2048 + w * 512), 16, 0, 0);
        const unsigned short* gb = Bb + (size_t)(n0 + r * 64 + srow) * ldb + (k0 + c * 32 + skoff);
        __builtin_amdgcn_global_load_lds((gvoid_t*)gb, (lvoid_t*)(Bs + c * 4096 + r * 2048 + w * 512), 16, 0, 0);
      }
    }
    __syncthreads();

#pragma unroll
    for (int c = 0; c < 2; ++c) {
      short8 af[4], bf[4];
#pragma unroll
      for (int i = 0; i < 4; ++i)
        af[i] = *(const short8*)(As + c * 4096 + (wr * 64 + i * 16 + lo) * 32 + quad * 8);
#pragma unroll
      for (int j = 0; j < 4; ++j)
        bf[j] = *(const short8*)(Bs + c * 4096 + (wc * 64 + j * 16 + lo) * 32 + quad * 8);

#pragma unroll
      for (int i = 0; i < 4; ++i)
#pragma unroll
        for (int j = 0; j < 4; ++j)
          acc[i][j] = __builtin_amdgcn_mfma_f32_16x16x32_bf16(af[i], bf[j], acc[i][j], 0, 0, 0);
    }
    __syncthreads();
  }
}

// ---------------- epilogue helpers ----------------
// mode 0: v += bias[ct] ; mode 2: v = exp(min(v*scale,30)) ; mode 3: v *= rlrow[rt+r]
__device__ __forceinline__ void tile_to_lds(
    unsigned short* Ls, f32x4 (&acc)[4][4], int mode,
    const unsigned short* bias_n0, const float* rlrow, float scale)
{
  const int t = threadIdx.x;
  const int w = t >> 6, lane = t & 63;
  const int lo = lane & 15, quad = lane >> 4, wr = w >> 1, wc = w & 1;
#pragma unroll
  for (int j = 0; j < 4; ++j) {
    const int ct = wc * 64 + j * 16 + lo;
    const float bv = (mode == 0) ? b2f(bias_n0[ct]) : 0.f;
#pragma unroll
    for (int i = 0; i < 4; ++i) {
      const int rt = wr * 64 + i * 16 + quad * 4;
#pragma unroll
      for (int r = 0; r < 4; ++r) {
        float v = acc[i][j][r];
        if (mode == 0)      v += bv;
        else if (mode == 2) v = __expf(fminf(v * scale, 30.f));
        else                v *= rlrow[rt + r];
        Ls[(rt + r) * 136 + ct] = f2b(v);
      }
    }
  }
  __syncthreads();
}

__device__ __forceinline__ void lds_to_global_bf16(
    const unsigned short* Ls, unsigned short* Cg, int ldc)
{
  const int t = threadIdx.x;
  const int cr = t >> 4, cc = (t & 15) * 8;
#pragma unroll
  for (int r0 = 0; r0 < 128; r0 += 16) {
    uint4 v = *(const uint4*)(Ls + (r0 + cr) * 136 + cc);
    *(uint4*)(Cg + (size_t)(r0 + cr) * ldc + cc) = v;
  }
}

// ---------------- qkv: fused projections ----------------
__global__ __launch_bounds__(256, 2) void qkv_k(
    const unsigned short* __restrict__ x0, const unsigned short* __restrict__ x1,
    const unsigned short* __restrict__ Wq0, const unsigned short* __restrict__ Wq1,
    const unsigned short* __restrict__ bq0, const unsigned short* __restrict__ bq1,
    const unsigned short* __restrict__ Wk0, const unsigned short* __restrict__ Wk1,
    const unsigned short* __restrict__ bk0, const unsigned short* __restrict__ bk1,
    const unsigned short* __restrict__ Wv0, const unsigned short* __restrict__ Wv1,
    const unsigned short* __restrict__ bv0, const unsigned short* __restrict__ bv1,
    unsigned short* __restrict__ qb, unsigned short* __restrict__ kb,
    unsigned short* __restrict__ vt, const int* __restrict__ flagp)
{
  __shared__ unsigned short smem[17408];
  const int flg = flagp[0];
  const int sel = blockIdx.y / 6;
  const int n0  = (blockIdx.y % 6) * 128;
  const int m0  = blockIdx.x * 128;

  const unsigned short* A = flg ? x0 : x1;
  const unsigned short* W;
  const unsigned short* bi;
  if (sel == 0)      { W = flg ? Wq0 : Wq1; bi = flg ? bq0 : bq1; }
  else if (sel == 1) { W = flg ? Wk0 : Wk1; bi = flg ? bk0 : bk1; }
  else               { W = flg ? Wv0 : Wv1; bi = flg ? bv0 : bv1; }

  f32x4 acc[4][4] = {};
  gemm_core(A, W, 768, 768, 768, m0, n0, smem, smem + 8192, acc);

  const int t = threadIdx.x;
  const int w = t >> 6, lane = t & 63;
  const int lo = lane & 15, quad = lane >> 4, wr = w >> 1, wc = w & 1;

  if (sel < 2) {
    tile_to_lds(smem, acc, 0, bi + n0, nullptr, 0.f);
    unsigned short* dst = (sel == 0) ? qb : kb;
    lds_to_global_bf16(smem, dst + (size_t)m0 * 768 + n0, 768);
    return;
  }

  // V: transpose epilogue into Vt[b][e][s]  (Ls as [col][row], stride 136)
  unsigned short* Ls = smem;
#pragma unroll
  for (int i = 0; i < 4; ++i) {
    const int rt = wr * 64 + i * 16 + quad * 4;
#pragma unroll
    for (int j = 0; j < 4; ++j) {
      const int ct = wc * 64 + j * 16 + lo;
      const float bvv = b2f(bi[n0 + ct]);
      ushort4 pk;
      pk.x = f2b(acc[i][j][0] + bvv);
      pk.y = f2b(acc[i][j][1] + bvv);
      pk.z = f2b(acc[i][j][2] + bvv);
      pk.w = f2b(acc[i][j][3] + bvv);
      *(ushort4*)(Ls + ct * 136 + rt) = pk;
    }
  }
  __syncthreads();
  const int bb  = m0 >> 11;
  const int sin = m0 & 2047;
  unsigned short* Cb = vt + (size_t)bb * (768 * 2048);
#pragma unroll
  for (int e0 = 0; e0 < 128; e0 += 16) {
    const int et = e0 + (t >> 4);
    const int st = (t & 15) * 8;
    uint4 val = *(const uint4*)(Ls + et * 136 + st);
    *(uint4*)(Cb + (size_t)(n0 + et) * 2048 + (sin + st)) = val;
  }
}

// ---------------- score: E = exp(QK^T/sqrt(D)) + fused rowsum ----------------
__global__ __launch_bounds__(256, 2) void score_k(
    const unsigned short* __restrict__ Q, const unsigned short* __restrict__ Kb,
    unsigned short* __restrict__ E, float* __restrict__ rl, float scale)
{
  __shared__ unsigned short smem[17408];
  const int m0 = blockIdx.x * 128, n0 = blockIdx.y * 128, bz = blockIdx.z;

  f32x4 acc[4][4] = {};
  gemm_core(Q + (size_t)bz * 1572864, Kb + (size_t)bz * 1572864,
            768, 768, 768, m0, n0, smem, smem + 8192, acc);

  tile_to_lds(smem, acc, 2, nullptr, nullptr, scale);
  lds_to_global_bf16(smem, E + (size_t)bz * 4194304 + (size_t)m0 * 2048 + n0, 2048);

  // fused partial rowsum from the staged LDS tile
  const int t = threadIdx.x;
  const int row = t >> 1, half = t & 1;
  const unsigned short* lr = smem + row * 136 + half * 64;
  float s = 0.f;
#pragma unroll
  for (int q8 = 0; q8 < 8; ++q8) {
    uint4 v = *(const uint4*)(lr + q8 * 8);
    unsigned int uu[4] = {v.x, v.y, v.z, v.w};
#pragma unroll
    for (int c = 0; c < 4; ++c)
      s += b2f((unsigned short)(uu[c] & 0xffffu)) + b2f((unsigned short)(uu[c] >> 16));
  }
  s += __shfl_xor(s, 1);
  if (half == 0) atomicAdd(rl + bz * 2048 + m0 + row, s);
}

__global__ __launch_bounds__(256) void inv_k(float* __restrict__ rl) {
  const int i = blockIdx.x * 256 + threadIdx.x;
  if (i < 16384) rl[i] = 1.0f / fmaxf(rl[i], 1e-30f);
}

// ---------------- pv: attn = (E @ V) * rl ----------------
__global__ __launch_bounds__(256, 2) void pv_k(
    const unsigned short* __restrict__ E, const unsigned short* __restrict__ Vt,
    const float* __restrict__ rl, unsigned short* __restrict__ attn)
{
  __shared__ unsigned short smem[17408];
  const int m0 = blockIdx.x * 128, n0 = blockIdx.y * 128, bz = blockIdx.z;

  f32x4 acc[4][4] = {};
  gemm_core(E + (size_t)bz * 4194304, Vt + (size_t)bz * 1572864,
            2048, 2048, 2048, m0, n0, smem, smem + 8192, acc);

  tile_to_lds(smem, acc, 3, nullptr, rl + bz * 2048 + m0, 0.f);
  lds_to_global_bf16(smem, attn + (size_t)bz * 1572864 + (size_t)m0 * 768 + n0, 768);
}

// ---------------- out: final projection ----------------
__global__ __launch_bounds__(256, 2) void out_k(
    const unsigned short* __restrict__ attn,
    const unsigned short* __restrict__ Wp0, const unsigned short* __restrict__ Wp1,
    const unsigned short* __restrict__ bp0, const unsigned short* __restrict__ bp1,
    void* __restrict__ outp, const int* __restrict__ flagp)
{
  __shared__ unsigned short smem[17408];
  const int flg = flagp[0];
  const int m0 = blockIdx.x * 128, n0 = blockIdx.y * 128;
  const unsigned short* W  = flg ? Wp0 : Wp1;
  const unsigned short* bi = flg ? bp0 : bp1;

  f32x4 acc[4][4] = {};
  gemm_core(attn, W, 768, 768, 768, m0, n0, smem, smem + 8192, acc);

  if (flg) {
    tile_to_lds(smem, acc, 0, bi + n0, nullptr, 0.f);
    lds_to_global_bf16(smem, (unsigned short*)outp + (size_t)m0 * 768 + n0, 768);
    return;
  }

  // fp32 output: two half-tiles (cols 0-63 then 64-127) staged as float through LDS
  const int t = threadIdx.x;
  const int w = t >> 6, lane = t & 63;
  const int lo = lane & 15, quad = lane >> 4, wr = w >> 1, wc = w & 1;
  float* Lf = (float*)smem;     // 128 x 68 floats = 34816 B
  float* Of = (float*)outp;
#pragma unroll
  for (int h = 0; h < 2; ++h) {
    __syncthreads();
    if (wc == h) {
#pragma unroll
      for (int j = 0; j < 4; ++j) {
        const int cl = j * 16 + lo;                 // 0..63 within half
        const float bvv = b2f(bi[n0 + h * 64 + cl]);
#pragma unroll
        for (int i = 0; i < 4; ++i) {
          const int rt = wr * 64 + i * 16 + quad * 4;
#pragma unroll
          for (int r = 0; r < 4; ++r)
            Lf[(rt + r) * 68 + cl] = acc[i][j][r] + bvv;
        }
      }
    }
    __syncthreads();
    const int cr = t >> 4, cc = (t & 15) * 4;
#pragma unroll
    for (int r0 = 0; r0 < 128; r0 += 16) {
      float4 v = *(const float4*)(Lf + (r0 + cr) * 68 + cc);
      *(float4*)(Of + (size_t)(m0 + r0 + cr) * 768 + n0 + h * 64 + cc) = v;
    }
  }
}

extern "C" void kernel_launch(void* const* d_in, const int* in_sizes, int n_in,
                              void* d_out, int out_size, void* d_ws, size_t ws_size,
                              hipStream_t stream) {
  (void)in_sizes; (void)n_in; (void)out_size; (void)ws_size;
  const unsigned short* x  = (const unsigned short*)d_in[0];
  const unsigned short* Wq = (const unsigned short*)d_in[1];
  const unsigned short* bq = (const unsigned short*)d_in[2];
  const unsigned short* Wk = (const unsigned short*)d_in[3];
  const unsigned short* bk = (const unsigned short*)d_in[4];
  const unsigned short* Wv = (const unsigned short*)d_in[5];
  const unsigned short* bv = (const unsigned short*)d_in[6];
  const unsigned short* Wp = (const unsigned short*)d_in[7];
  const unsigned short* bp = (const unsigned short*)d_in[8];

  char* ws = (char*)d_ws;
  int*   flagp = (int*)ws;
  float* rl    = (float*)(ws + 4096);
  unsigned short* wcv = (unsigned short*)(ws + ((size_t)1 << 20));
  unsigned short* qb  = (unsigned short*)(ws + ((size_t)8  << 20));
  unsigned short* kb  = (unsigned short*)(ws + ((size_t)32 << 20));
  unsigned short* vt  = (unsigned short*)(ws + ((size_t)56 << 20));
  unsigned short* eb  = (unsigned short*)(ws + ((size_t)80 << 20));
  unsigned short* xb  = eb;     // converted x aliases E (x dead before score_k writes E)
  unsigned short* attn = qb;    // Q dead after score_k

  unsigned short* wqb = wcv;
  unsigned short* bqb = wcv + 589824;
  unsigned short* wkb = wcv + 590592;
  unsigned short* bkb = wcv + 1180416;
  unsigned short* wvb = wcv + 1181184;
  unsigned short* bvb = wcv + 1771008;
  unsigned short* wpb = wcv + 1771776;
  unsigned short* bpb = wcv + 2361600;

  const float inv_scale = 0.036084391824351615f;  // 1/sqrt(768)
  dim3 blk(256);

  detect_dtype<<<1, 256, 0, stream>>>((const unsigned int*)d_in[0], flagp);

  Cvt9 cv;
  cv.s[0] = d_in[0]; cv.d[0] = xb;  cv.n8[0] = 12582912 / 8;
  cv.s[1] = d_in[1]; cv.d[1] = wqb; cv.n8[1] = 589824 / 8;
  cv.s[2] = d_in[2]; cv.d[2] = bqb; cv.n8[2] = 768 / 8;
  cv.s[3] = d_in[3]; cv.d[3] = wkb; cv.n8[3] = 589824 / 8;
  cv.s[4] = d_in[4]; cv.d[4] = bkb; cv.n8[4] = 768 / 8;
  cv.s[5] = d_in[5]; cv.d[5] = wvb; cv.n8[5] = 589824 / 8;
  cv.s[6] = d_in[6]; cv.d[6] = bvb; cv.n8[6] = 768 / 8;
  cv.s[7] = d_in[7]; cv.d[7] = wpb; cv.n8[7] = 589824 / 8;
  cv.s[8] = d_in[8]; cv.d[8] = bpb; cv.n8[8] = 768 / 8;
  cv.total8 = (12582912 + 4 * (589824 + 768)) / 8;
  convert_inputs<<<(unsigned)((cv.total8 + 255) / 256), blk, 0, stream>>>(cv, flagp);

  hipMemsetAsync(rl, 0, 16384 * sizeof(float), stream);

  qkv_k<<<dim3(128, 18, 1), blk, 0, stream>>>(
      x, xb, Wq, wqb, bq, bqb, Wk, wkb, bk, bkb, Wv, wvb, bv, bvb,
      qb, kb, vt, flagp);

  score_k<<<dim3(16, 16, 8), blk, 0, stream>>>(qb, kb, eb, rl, inv_scale);

  inv_k<<<64, blk, 0, stream>>>(rl);

  pv_k<<<dim3(16, 6, 8), blk, 0, stream>>>(eb, vt, rl, attn);

  out_k<<<dim3(128, 6, 1), blk, 0, stream>>>(attn, Wp, wpb, bp, bpb, d_out, flagp);
}